// Round 4
// baseline (717.132 us; speedup 1.0000x reference)
//
#include <hip/hip_runtime.h>

#define NN 50000
#define EE 800000
#define DD 128
#define CC 64

// ---------------- CSR build ----------------

__global__ __launch_bounds__(256) void k_degree(const int* __restrict__ dst,
                                                int* __restrict__ deg) {
    int e = blockIdx.x * 256 + threadIdx.x;
    if (e < EE) atomicAdd(&deg[dst[e]], 1);
}

__global__ __launch_bounds__(1024) void k_scan(const int* __restrict__ deg,
                                               int* __restrict__ row_off,
                                               float* __restrict__ inv_deg) {
    __shared__ int sd[1024];
    int t = threadIdx.x;
    int carry = 0;
    for (int base = 0; base < NN; base += 1024) {
        int i = base + t;
        int v = (i < NN) ? deg[i] : 0;
        sd[t] = v;
        __syncthreads();
        int x = v;
        for (int off = 1; off < 1024; off <<= 1) {
            int y = (t >= off) ? sd[t - off] : 0;
            __syncthreads();
            x += y;
            sd[t] = x;
            __syncthreads();
        }
        if (i < NN) {
            row_off[i] = carry + x - v;            // exclusive scan
            inv_deg[i] = 1.0f / fmaxf((float)v, 1.0f);
        }
        carry += sd[1023];
        __syncthreads();
    }
    if (t == 0) row_off[NN] = carry;               // == EE
}

__global__ __launch_bounds__(256) void k_fill(const int* __restrict__ src,
                                              const int* __restrict__ dst,
                                              const int* __restrict__ row_off,
                                              int* __restrict__ cursor,
                                              int* __restrict__ csr) {
    int e = blockIdx.x * 256 + threadIdx.x;
    if (e < EE) {
        int d = dst[e];
        int pos = atomicAdd(&cursor[d], 1);
        csr[row_off[d] + pos] = src[e];
    }
}

// ---------------- mean aggregation: one wave per destination node ----------------

__global__ __launch_bounds__(256) void k_agg(const float* __restrict__ h,
                                             const int* __restrict__ row_off,
                                             const int* __restrict__ csr,
                                             const float* __restrict__ inv_deg,
                                             float* __restrict__ agg) {
    int wave = blockIdx.x * 4 + (threadIdx.x >> 6);
    int lane = threadIdx.x & 63;
    if (wave >= NN) return;
    int beg = row_off[wave], end = row_off[wave + 1];
    float a0 = 0.f, a1 = 0.f;
    for (int e = beg; e < end; ++e) {
        int s = csr[e];
        float2 v = ((const float2*)(h + (size_t)s * DD))[lane];
        a0 += v.x;
        a1 += v.y;
    }
    float sc = inv_deg[wave];
    ((float2*)(agg + (size_t)wave * DD))[lane] = make_float2(a0 * sc, a1 * sc);
}

// ---------------- fused SAGEConv layer: h@Ws + agg@Wn + b + resid [+relu+LN] ----------------
// block: 256 threads, 64 nodes. thread t: cols [ (t&31)*4, +4 ), nodes [ (t>>5)*8, +8 )

__device__ __forceinline__ void stage_tile(const float* __restrict__ g, int b0,
                                           float* __restrict__ tile, int t) {
#pragma unroll
    for (int j = 0; j < 8; ++j) {
        int idx = t + 256 * j;     // 2048 float4-groups = 64 rows x 128 cols
        int r = idx >> 5;
        int c = idx & 31;
        int node = b0 + r;
        float4 f = make_float4(0.f, 0.f, 0.f, 0.f);
        if (node < NN) f = *(const float4*)(g + (size_t)node * DD + c * 4);
        *(float4*)&tile[r * DD + c * 4] = f;
    }
}

__global__ __launch_bounds__(256) void k_gemm(const float* __restrict__ h_in,
                                              const float* __restrict__ agg,
                                              const float* __restrict__ Ws,
                                              const float* __restrict__ Wn,
                                              const float* __restrict__ bias,
                                              const float* __restrict__ gmm,
                                              const float* __restrict__ bet,
                                              float* __restrict__ h_out,
                                              float* __restrict__ emb_out,
                                              int do_ln) {
    __shared__ float tile[64 * DD];    // 32 KB
    int t = threadIdx.x;
    int b0 = blockIdx.x * 64;
    int cg = t & 31;
    int ng = t >> 5;
    float acc[8][4];
#pragma unroll
    for (int i = 0; i < 8; ++i)
#pragma unroll
        for (int j = 0; j < 4; ++j) acc[i][j] = 0.f;

    // ---- phase 1: h @ Wself ----
    stage_tile(h_in, b0, tile, t);
    __syncthreads();
    for (int k = 0; k < DD; k += 4) {
        float4 w0 = *(const float4*)(Ws + (k + 0) * DD + cg * 4);
        float4 w1 = *(const float4*)(Ws + (k + 1) * DD + cg * 4);
        float4 w2 = *(const float4*)(Ws + (k + 2) * DD + cg * 4);
        float4 w3 = *(const float4*)(Ws + (k + 3) * DD + cg * 4);
#pragma unroll
        for (int i = 0; i < 8; ++i) {
            float4 hv = *(const float4*)&tile[(ng * 8 + i) * DD + k];
            acc[i][0] = fmaf(hv.x, w0.x, fmaf(hv.y, w1.x, fmaf(hv.z, w2.x, fmaf(hv.w, w3.x, acc[i][0]))));
            acc[i][1] = fmaf(hv.x, w0.y, fmaf(hv.y, w1.y, fmaf(hv.z, w2.y, fmaf(hv.w, w3.y, acc[i][1]))));
            acc[i][2] = fmaf(hv.x, w0.z, fmaf(hv.y, w1.z, fmaf(hv.z, w2.z, fmaf(hv.w, w3.z, acc[i][2]))));
            acc[i][3] = fmaf(hv.x, w0.w, fmaf(hv.y, w1.w, fmaf(hv.z, w2.w, fmaf(hv.w, w3.w, acc[i][3]))));
        }
    }
    // residual (tile still holds h_in)
#pragma unroll
    for (int i = 0; i < 8; ++i) {
        float4 r4 = *(const float4*)&tile[(ng * 8 + i) * DD + cg * 4];
        acc[i][0] += r4.x; acc[i][1] += r4.y; acc[i][2] += r4.z; acc[i][3] += r4.w;
    }
    __syncthreads();

    // ---- phase 2: agg @ Wneigh ----
    stage_tile(agg, b0, tile, t);
    __syncthreads();
    for (int k = 0; k < DD; k += 4) {
        float4 w0 = *(const float4*)(Wn + (k + 0) * DD + cg * 4);
        float4 w1 = *(const float4*)(Wn + (k + 1) * DD + cg * 4);
        float4 w2 = *(const float4*)(Wn + (k + 2) * DD + cg * 4);
        float4 w3 = *(const float4*)(Wn + (k + 3) * DD + cg * 4);
#pragma unroll
        for (int i = 0; i < 8; ++i) {
            float4 hv = *(const float4*)&tile[(ng * 8 + i) * DD + k];
            acc[i][0] = fmaf(hv.x, w0.x, fmaf(hv.y, w1.x, fmaf(hv.z, w2.x, fmaf(hv.w, w3.x, acc[i][0]))));
            acc[i][1] = fmaf(hv.x, w0.y, fmaf(hv.y, w1.y, fmaf(hv.z, w2.y, fmaf(hv.w, w3.y, acc[i][1]))));
            acc[i][2] = fmaf(hv.x, w0.z, fmaf(hv.y, w1.z, fmaf(hv.z, w2.z, fmaf(hv.w, w3.z, acc[i][2]))));
            acc[i][3] = fmaf(hv.x, w0.w, fmaf(hv.y, w1.w, fmaf(hv.z, w2.w, fmaf(hv.w, w3.w, acc[i][3]))));
        }
    }

    // bias
    {
        float4 b4 = *(const float4*)(bias + cg * 4);
#pragma unroll
        for (int i = 0; i < 8; ++i) {
            acc[i][0] += b4.x; acc[i][1] += b4.y; acc[i][2] += b4.z; acc[i][3] += b4.w;
        }
    }

    if (do_ln) {
        float4 g4 = *(const float4*)(gmm + cg * 4);
        float4 e4 = *(const float4*)(bet + cg * 4);
#pragma unroll
        for (int i = 0; i < 8; ++i) {
#pragma unroll
            for (int j = 0; j < 4; ++j) acc[i][j] = fmaxf(acc[i][j], 0.f);
            float s = acc[i][0] + acc[i][1] + acc[i][2] + acc[i][3];
            float q = acc[i][0] * acc[i][0] + acc[i][1] * acc[i][1] +
                      acc[i][2] * acc[i][2] + acc[i][3] * acc[i][3];
            // reduce over the 32 threads sharing this node (lanes 0-31 or 32-63)
#pragma unroll
            for (int m = 1; m < 32; m <<= 1) {
                s += __shfl_xor(s, m);
                q += __shfl_xor(q, m);
            }
            float mu = s * (1.0f / 128.0f);
            float var = fmaxf(q * (1.0f / 128.0f) - mu * mu, 0.f);
            float rs = rsqrtf(var + 1e-5f);
            acc[i][0] = g4.x * (acc[i][0] - mu) * rs + e4.x;
            acc[i][1] = g4.y * (acc[i][1] - mu) * rs + e4.y;
            acc[i][2] = g4.z * (acc[i][2] - mu) * rs + e4.z;
            acc[i][3] = g4.w * (acc[i][3] - mu) * rs + e4.w;
        }
    }

    // store fp32 h_out (+ optional fp32 embedding to d_out)
#pragma unroll
    for (int i = 0; i < 8; ++i) {
        int node = b0 + ng * 8 + i;
        if (node < NN) {
            float4 o4 = make_float4(acc[i][0], acc[i][1], acc[i][2], acc[i][3]);
            *(float4*)(h_out + (size_t)node * DD + cg * 4) = o4;
            if (emb_out) *(float4*)(emb_out + (size_t)node * DD + cg * 4) = o4;
        }
    }
}

// ---------------- output head: logits = h @ Wout + bout ----------------
// block 256 threads, 64 nodes. thread t: cols [(t&15)*4,+4), nodes [(t>>4)*4,+4)

__global__ __launch_bounds__(256) void k_logits(const float* __restrict__ h,
                                                const float* __restrict__ Wo,
                                                const float* __restrict__ bo,
                                                float* __restrict__ out) {
    __shared__ float tile[64 * DD];
    int t = threadIdx.x;
    int b0 = blockIdx.x * 64;
    int cg = t & 15;
    int ng = t >> 4;
    stage_tile(h, b0, tile, t);
    __syncthreads();
    float acc[4][4];
#pragma unroll
    for (int i = 0; i < 4; ++i)
#pragma unroll
        for (int j = 0; j < 4; ++j) acc[i][j] = 0.f;
    for (int k = 0; k < DD; k += 4) {
        float4 w0 = *(const float4*)(Wo + (k + 0) * CC + cg * 4);
        float4 w1 = *(const float4*)(Wo + (k + 1) * CC + cg * 4);
        float4 w2 = *(const float4*)(Wo + (k + 2) * CC + cg * 4);
        float4 w3 = *(const float4*)(Wo + (k + 3) * CC + cg * 4);
#pragma unroll
        for (int i = 0; i < 4; ++i) {
            float4 hv = *(const float4*)&tile[(ng * 4 + i) * DD + k];
            acc[i][0] = fmaf(hv.x, w0.x, fmaf(hv.y, w1.x, fmaf(hv.z, w2.x, fmaf(hv.w, w3.x, acc[i][0]))));
            acc[i][1] = fmaf(hv.x, w0.y, fmaf(hv.y, w1.y, fmaf(hv.z, w2.y, fmaf(hv.w, w3.y, acc[i][1]))));
            acc[i][2] = fmaf(hv.x, w0.z, fmaf(hv.y, w1.z, fmaf(hv.z, w2.z, fmaf(hv.w, w3.z, acc[i][2]))));
            acc[i][3] = fmaf(hv.x, w0.w, fmaf(hv.y, w1.w, fmaf(hv.z, w2.w, fmaf(hv.w, w3.w, acc[i][3]))));
        }
    }
    float4 b4 = *(const float4*)(bo + cg * 4);
#pragma unroll
    for (int i = 0; i < 4; ++i) {
        int node = b0 + ng * 4 + i;
        if (node < NN) {
            *(float4*)(out + (size_t)node * CC + cg * 4) =
                make_float4(acc[i][0] + b4.x, acc[i][1] + b4.y,
                            acc[i][2] + b4.z, acc[i][3] + b4.w);
        }
    }
}

// ---------------- launch ----------------

extern "C" void kernel_launch(void* const* d_in, const int* in_sizes, int n_in,
                              void* d_out, int out_size, void* d_ws, size_t ws_size,
                              hipStream_t stream) {
    const float* x  = (const float*)d_in[0];
    const int* src  = (const int*)d_in[1];
    const int* dst  = (const int*)d_in[2];
    const float* Ws = (const float*)d_in[3];
    const float* Wn = (const float*)d_in[4];
    const float* bc = (const float*)d_in[5];
    const float* gm = (const float*)d_in[6];
    const float* bt = (const float*)d_in[7];
    const float* Wo = (const float*)d_in[8];
    const float* bo = (const float*)d_in[9];
    float* out = (float*)d_out;   // fp32: logits [NN*CC] then embedding [NN*DD]

    char* p = (char*)d_ws;
    auto alloc = [&](size_t bytes) { void* r = (void*)p; p += (bytes + 255) & ~(size_t)255; return r; };
    float* h0    = (float*)alloc((size_t)NN * DD * 4);
    float* h1    = (float*)alloc((size_t)NN * DD * 4);
    float* ag    = (float*)alloc((size_t)NN * DD * 4);
    float* invd  = (float*)alloc(NN * 4);
    int* deg     = (int*)alloc(NN * 4);
    int* row_off = (int*)alloc((NN + 1) * 4);
    int* cursor  = (int*)alloc(NN * 4);
    int* csr     = (int*)alloc(EE * 4);

    hipMemsetAsync(deg, 0, NN * 4, stream);
    hipMemsetAsync(cursor, 0, NN * 4, stream);

    k_degree<<<(EE + 255) / 256, 256, 0, stream>>>(dst, deg);
    k_scan<<<1, 1024, 0, stream>>>(deg, row_off, invd);
    k_fill<<<(EE + 255) / 256, 256, 0, stream>>>(src, dst, row_off, cursor, csr);

    const float* hin = x;
    float* houts[3] = {h0, h1, h0};
    for (int l = 0; l < 3; ++l) {
        k_agg<<<(NN + 3) / 4, 256, 0, stream>>>(hin, row_off, csr, invd, ag);
        k_gemm<<<(NN + 63) / 64, 256, 0, stream>>>(
            hin, ag, Ws + l * DD * DD, Wn + l * DD * DD, bc + l * DD,
            (l < 2) ? gm + l * DD : (const float*)nullptr,
            (l < 2) ? bt + l * DD : (const float*)nullptr,
            houts[l], (l == 2) ? out + (size_t)NN * CC : (float*)nullptr,
            (l < 2) ? 1 : 0);
        hin = houts[l];
    }
    k_logits<<<(NN + 63) / 64, 256, 0, stream>>>(h0, Wo, bo, out);
}

// Round 5
// 513.421 us; speedup vs baseline: 1.3968x; 1.3968x over previous
//
#include <hip/hip_runtime.h>

#define NN 50000
#define EE 800000
#define DD 128
#define CC 64
#define SCAN_B 512
#define NBLK ((NN + SCAN_B - 1) / SCAN_B)   // 98

typedef unsigned short u16;
typedef unsigned int u32;

__device__ __forceinline__ float bf2f(u16 u) {
    union { u32 i; float f; } v; v.i = ((u32)u) << 16; return v.f;
}
__device__ __forceinline__ u16 f2bf(float f) {
    union { float f; u32 i; } v; v.f = f;
    u32 x = v.i;
    u32 r = x + 0x7fffu + ((x >> 16) & 1u);   // round-to-nearest-even
    return (u16)(r >> 16);
}

// ---------------- degree ----------------

__global__ __launch_bounds__(256) void k_degree(const int* __restrict__ dst,
                                                int* __restrict__ deg) {
    int e = blockIdx.x * 256 + threadIdx.x;
    if (e < EE) atomicAdd(&deg[dst[e]], 1);
}

// ---------------- 3-phase exclusive scan over deg -> row_off, inv_deg ----------------

__global__ __launch_bounds__(512) void k_bsum(const int* __restrict__ deg,
                                              int* __restrict__ bsum) {
    __shared__ int ws[8];
    int b = blockIdx.x, t = threadIdx.x;
    int i = b * SCAN_B + t;
    int x = (i < NN) ? deg[i] : 0;
#pragma unroll
    for (int o = 1; o < 64; o <<= 1) x += __shfl_xor(x, o);
    if ((t & 63) == 0) ws[t >> 6] = x;
    __syncthreads();
    if (t == 0) {
        int s = 0;
#pragma unroll
        for (int w = 0; w < 8; ++w) s += ws[w];
        bsum[b] = s;
    }
}

__global__ __launch_bounds__(128) void k_bscan(int* __restrict__ bsum,
                                               int* __restrict__ row_off) {
    __shared__ int w0sum;
    int t = threadIdx.x;
    int v = (t < NBLK) ? bsum[t] : 0;
    int x = v;
#pragma unroll
    for (int o = 1; o < 64; o <<= 1) {
        int y = __shfl_up(x, o, 64);
        if ((t & 63) >= o) x += y;
    }
    if (t == 63) w0sum = x;
    __syncthreads();
    if (t >= 64) x += w0sum;
    if (t < NBLK) bsum[t] = x - v;       // exclusive
    if (t == NBLK - 1) row_off[NN] = x;  // total == EE
}

__global__ __launch_bounds__(512) void k_cscan(const int* __restrict__ deg,
                                               const int* __restrict__ bsum,
                                               int* __restrict__ row_off,
                                               float* __restrict__ inv_deg) {
    __shared__ int ws[8];
    int b = blockIdx.x, t = threadIdx.x;
    int i = b * SCAN_B + t;
    int v = (i < NN) ? deg[i] : 0;
    int lane = t & 63, wid = t >> 6;
    int x = v;
#pragma unroll
    for (int o = 1; o < 64; o <<= 1) {
        int y = __shfl_up(x, o, 64);
        if (lane >= o) x += y;
    }
    if (lane == 63) ws[wid] = x;
    __syncthreads();
    int woff = 0;
    for (int w = 0; w < wid; ++w) woff += ws[w];
    if (i < NN) {
        row_off[i] = bsum[b] + woff + x - v;
        inv_deg[i] = 1.0f / fmaxf((float)v, 1.0f);
    }
}

__global__ __launch_bounds__(256) void k_fill(const int* __restrict__ src,
                                              const int* __restrict__ dst,
                                              const int* __restrict__ row_off,
                                              int* __restrict__ cursor,
                                              int* __restrict__ csr) {
    int e = blockIdx.x * 256 + threadIdx.x;
    if (e < EE) {
        int d = dst[e];
        int pos = atomicAdd(&cursor[d], 1);
        csr[row_off[d] + pos] = src[e];
    }
}

// ---------------- x -> bf16 shadow (gather path only) ----------------

__global__ __launch_bounds__(256) void k_x2bf(const float* __restrict__ x,
                                              u16* __restrict__ xb) {
    int i = (blockIdx.x * 256 + threadIdx.x) * 4;
    if (i < NN * DD) {
        float4 v = *(const float4*)(x + i);
        uint2 p;
        p.x = (u32)f2bf(v.x) | ((u32)f2bf(v.y) << 16);
        p.y = (u32)f2bf(v.z) | ((u32)f2bf(v.w) << 16);
        *(uint2*)(xb + i) = p;
    }
}

// ---------------- mean aggregation: one wave per node, bf16 gather ----------------
// half-waves process alternating edges: 32 lanes x uint2 (4 bf16) = 256 B/row.

__global__ __launch_bounds__(256) void k_agg(const u16* __restrict__ hb,
                                             const int* __restrict__ row_off,
                                             const int* __restrict__ csr,
                                             const float* __restrict__ inv_deg,
                                             float* __restrict__ agg) {
    int wave = blockIdx.x * 4 + (threadIdx.x >> 6);
    int lane = threadIdx.x & 63;
    if (wave >= NN) return;
    int half = lane >> 5;
    int l32 = lane & 31;
    int beg = row_off[wave], end = row_off[wave + 1];
    float a0 = 0.f, a1 = 0.f, a2 = 0.f, a3 = 0.f;
#pragma unroll 4
    for (int e = beg + half; e < end; e += 2) {
        int s = csr[e];
        uint2 u = *(const uint2*)(hb + (size_t)s * DD + l32 * 4);
        a0 += bf2f((u16)(u.x & 0xffffu));
        a1 += bf2f((u16)(u.x >> 16));
        a2 += bf2f((u16)(u.y & 0xffffu));
        a3 += bf2f((u16)(u.y >> 16));
    }
    a0 += __shfl_xor(a0, 32);
    a1 += __shfl_xor(a1, 32);
    a2 += __shfl_xor(a2, 32);
    a3 += __shfl_xor(a3, 32);
    if (half == 0) {
        float sc = inv_deg[wave];
        *(float4*)(agg + (size_t)wave * DD + l32 * 4) =
            make_float4(a0 * sc, a1 * sc, a2 * sc, a3 * sc);
    }
}

// ---------------- fused SAGEConv layer ----------------
// block: 256 threads, 64 nodes. thread t: cols [ (t&31)*4, +4 ), nodes [ (t>>5)*8, +8 )

__device__ __forceinline__ void stage_tile(const float* __restrict__ g, int b0,
                                           float* __restrict__ tile, int t) {
#pragma unroll
    for (int j = 0; j < 8; ++j) {
        int idx = t + 256 * j;     // 2048 float4-groups = 64 rows x 128 cols
        int r = idx >> 5;
        int c = idx & 31;
        int node = b0 + r;
        float4 f = make_float4(0.f, 0.f, 0.f, 0.f);
        if (node < NN) f = *(const float4*)(g + (size_t)node * DD + c * 4);
        *(float4*)&tile[r * DD + c * 4] = f;
    }
}

__global__ __launch_bounds__(256) void k_gemm(const float* __restrict__ h_in,
                                              const float* __restrict__ agg,
                                              const float* __restrict__ Ws,
                                              const float* __restrict__ Wn,
                                              const float* __restrict__ bias,
                                              const float* __restrict__ gmm,
                                              const float* __restrict__ bet,
                                              float* __restrict__ h_out,
                                              u16* __restrict__ hb_out,
                                              float* __restrict__ emb_out,
                                              int do_ln) {
    __shared__ float tile[64 * DD];    // 32 KB
    int t = threadIdx.x;
    int b0 = blockIdx.x * 64;
    int cg = t & 31;
    int ng = t >> 5;
    float acc[8][4];
#pragma unroll
    for (int i = 0; i < 8; ++i)
#pragma unroll
        for (int j = 0; j < 4; ++j) acc[i][j] = 0.f;

    // ---- phase 1: h @ Wself ----
    stage_tile(h_in, b0, tile, t);
    __syncthreads();
    for (int k = 0; k < DD; k += 4) {
        float4 w0 = *(const float4*)(Ws + (k + 0) * DD + cg * 4);
        float4 w1 = *(const float4*)(Ws + (k + 1) * DD + cg * 4);
        float4 w2 = *(const float4*)(Ws + (k + 2) * DD + cg * 4);
        float4 w3 = *(const float4*)(Ws + (k + 3) * DD + cg * 4);
#pragma unroll
        for (int i = 0; i < 8; ++i) {
            float4 hv = *(const float4*)&tile[(ng * 8 + i) * DD + k];
            acc[i][0] = fmaf(hv.x, w0.x, fmaf(hv.y, w1.x, fmaf(hv.z, w2.x, fmaf(hv.w, w3.x, acc[i][0]))));
            acc[i][1] = fmaf(hv.x, w0.y, fmaf(hv.y, w1.y, fmaf(hv.z, w2.y, fmaf(hv.w, w3.y, acc[i][1]))));
            acc[i][2] = fmaf(hv.x, w0.z, fmaf(hv.y, w1.z, fmaf(hv.z, w2.z, fmaf(hv.w, w3.z, acc[i][2]))));
            acc[i][3] = fmaf(hv.x, w0.w, fmaf(hv.y, w1.w, fmaf(hv.z, w2.w, fmaf(hv.w, w3.w, acc[i][3]))));
        }
    }
    // residual (tile still holds h_in)
#pragma unroll
    for (int i = 0; i < 8; ++i) {
        float4 r4 = *(const float4*)&tile[(ng * 8 + i) * DD + cg * 4];
        acc[i][0] += r4.x; acc[i][1] += r4.y; acc[i][2] += r4.z; acc[i][3] += r4.w;
    }
    __syncthreads();

    // ---- phase 2: agg @ Wneigh ----
    stage_tile(agg, b0, tile, t);
    __syncthreads();
    for (int k = 0; k < DD; k += 4) {
        float4 w0 = *(const float4*)(Wn + (k + 0) * DD + cg * 4);
        float4 w1 = *(const float4*)(Wn + (k + 1) * DD + cg * 4);
        float4 w2 = *(const float4*)(Wn + (k + 2) * DD + cg * 4);
        float4 w3 = *(const float4*)(Wn + (k + 3) * DD + cg * 4);
#pragma unroll
        for (int i = 0; i < 8; ++i) {
            float4 hv = *(const float4*)&tile[(ng * 8 + i) * DD + k];
            acc[i][0] = fmaf(hv.x, w0.x, fmaf(hv.y, w1.x, fmaf(hv.z, w2.x, fmaf(hv.w, w3.x, acc[i][0]))));
            acc[i][1] = fmaf(hv.x, w0.y, fmaf(hv.y, w1.y, fmaf(hv.z, w2.y, fmaf(hv.w, w3.y, acc[i][1]))));
            acc[i][2] = fmaf(hv.x, w0.z, fmaf(hv.y, w1.z, fmaf(hv.z, w2.z, fmaf(hv.w, w3.z, acc[i][2]))));
            acc[i][3] = fmaf(hv.x, w0.w, fmaf(hv.y, w1.w, fmaf(hv.z, w2.w, fmaf(hv.w, w3.w, acc[i][3]))));
        }
    }

    // bias
    {
        float4 b4 = *(const float4*)(bias + cg * 4);
#pragma unroll
        for (int i = 0; i < 8; ++i) {
            acc[i][0] += b4.x; acc[i][1] += b4.y; acc[i][2] += b4.z; acc[i][3] += b4.w;
        }
    }

    if (do_ln) {
        float4 g4 = *(const float4*)(gmm + cg * 4);
        float4 e4 = *(const float4*)(bet + cg * 4);
#pragma unroll
        for (int i = 0; i < 8; ++i) {
#pragma unroll
            for (int j = 0; j < 4; ++j) acc[i][j] = fmaxf(acc[i][j], 0.f);
            float s = acc[i][0] + acc[i][1] + acc[i][2] + acc[i][3];
            float q = acc[i][0] * acc[i][0] + acc[i][1] * acc[i][1] +
                      acc[i][2] * acc[i][2] + acc[i][3] * acc[i][3];
#pragma unroll
            for (int m = 1; m < 32; m <<= 1) {
                s += __shfl_xor(s, m);
                q += __shfl_xor(q, m);
            }
            float mu = s * (1.0f / 128.0f);
            float var = fmaxf(q * (1.0f / 128.0f) - mu * mu, 0.f);
            float rs = rsqrtf(var + 1e-5f);
            acc[i][0] = g4.x * (acc[i][0] - mu) * rs + e4.x;
            acc[i][1] = g4.y * (acc[i][1] - mu) * rs + e4.y;
            acc[i][2] = g4.z * (acc[i][2] - mu) * rs + e4.z;
            acc[i][3] = g4.w * (acc[i][3] - mu) * rs + e4.w;
        }
    }

    // store fp32 h_out (+ bf16 shadow for next gather, + optional fp32 embedding)
#pragma unroll
    for (int i = 0; i < 8; ++i) {
        int node = b0 + ng * 8 + i;
        if (node < NN) {
            float4 o4 = make_float4(acc[i][0], acc[i][1], acc[i][2], acc[i][3]);
            *(float4*)(h_out + (size_t)node * DD + cg * 4) = o4;
            if (hb_out) {
                uint2 p;
                p.x = (u32)f2bf(o4.x) | ((u32)f2bf(o4.y) << 16);
                p.y = (u32)f2bf(o4.z) | ((u32)f2bf(o4.w) << 16);
                *(uint2*)(hb_out + (size_t)node * DD + cg * 4) = p;
            }
            if (emb_out) *(float4*)(emb_out + (size_t)node * DD + cg * 4) = o4;
        }
    }
}

// ---------------- output head: logits = h @ Wout + bout ----------------

__global__ __launch_bounds__(256) void k_logits(const float* __restrict__ h,
                                                const float* __restrict__ Wo,
                                                const float* __restrict__ bo,
                                                float* __restrict__ out) {
    __shared__ float tile[64 * DD];
    int t = threadIdx.x;
    int b0 = blockIdx.x * 64;
    int cg = t & 15;
    int ng = t >> 4;
    stage_tile(h, b0, tile, t);
    __syncthreads();
    float acc[4][4];
#pragma unroll
    for (int i = 0; i < 4; ++i)
#pragma unroll
        for (int j = 0; j < 4; ++j) acc[i][j] = 0.f;
    for (int k = 0; k < DD; k += 4) {
        float4 w0 = *(const float4*)(Wo + (k + 0) * CC + cg * 4);
        float4 w1 = *(const float4*)(Wo + (k + 1) * CC + cg * 4);
        float4 w2 = *(const float4*)(Wo + (k + 2) * CC + cg * 4);
        float4 w3 = *(const float4*)(Wo + (k + 3) * CC + cg * 4);
#pragma unroll
        for (int i = 0; i < 4; ++i) {
            float4 hv = *(const float4*)&tile[(ng * 4 + i) * DD + k];
            acc[i][0] = fmaf(hv.x, w0.x, fmaf(hv.y, w1.x, fmaf(hv.z, w2.x, fmaf(hv.w, w3.x, acc[i][0]))));
            acc[i][1] = fmaf(hv.x, w0.y, fmaf(hv.y, w1.y, fmaf(hv.z, w2.y, fmaf(hv.w, w3.y, acc[i][1]))));
            acc[i][2] = fmaf(hv.x, w0.z, fmaf(hv.y, w1.z, fmaf(hv.z, w2.z, fmaf(hv.w, w3.z, acc[i][2]))));
            acc[i][3] = fmaf(hv.x, w0.w, fmaf(hv.y, w1.w, fmaf(hv.z, w2.w, fmaf(hv.w, w3.w, acc[i][3]))));
        }
    }
    float4 b4 = *(const float4*)(bo + cg * 4);
#pragma unroll
    for (int i = 0; i < 4; ++i) {
        int node = b0 + ng * 4 + i;
        if (node < NN) {
            *(float4*)(out + (size_t)node * CC + cg * 4) =
                make_float4(acc[i][0] + b4.x, acc[i][1] + b4.y,
                            acc[i][2] + b4.z, acc[i][3] + b4.w);
        }
    }
}

// ---------------- launch ----------------

extern "C" void kernel_launch(void* const* d_in, const int* in_sizes, int n_in,
                              void* d_out, int out_size, void* d_ws, size_t ws_size,
                              hipStream_t stream) {
    const float* x  = (const float*)d_in[0];
    const int* src  = (const int*)d_in[1];
    const int* dst  = (const int*)d_in[2];
    const float* Ws = (const float*)d_in[3];
    const float* Wn = (const float*)d_in[4];
    const float* bc = (const float*)d_in[5];
    const float* gm = (const float*)d_in[6];
    const float* bt = (const float*)d_in[7];
    const float* Wo = (const float*)d_in[8];
    const float* bo = (const float*)d_in[9];
    float* out = (float*)d_out;   // fp32: logits [NN*CC] then embedding [NN*DD]

    char* p = (char*)d_ws;
    auto alloc = [&](size_t bytes) { void* r = (void*)p; p += (bytes + 255) & ~(size_t)255; return r; };
    float* h0    = (float*)alloc((size_t)NN * DD * 4);
    float* h1    = (float*)alloc((size_t)NN * DD * 4);
    float* ag    = (float*)alloc((size_t)NN * DD * 4);
    u16* xb      = (u16*)alloc((size_t)NN * DD * 2);
    u16* hb0     = (u16*)alloc((size_t)NN * DD * 2);
    u16* hb1     = (u16*)alloc((size_t)NN * DD * 2);
    float* invd  = (float*)alloc(NN * 4);
    int* deg     = (int*)alloc(NN * 4);
    int* row_off = (int*)alloc((NN + 1) * 4);
    int* cursor  = (int*)alloc(NN * 4);
    int* bsum    = (int*)alloc(NBLK * 4);
    int* csr     = (int*)alloc(EE * 4);

    hipMemsetAsync(deg, 0, NN * 4, stream);
    hipMemsetAsync(cursor, 0, NN * 4, stream);

    k_degree<<<(EE + 255) / 256, 256, 0, stream>>>(dst, deg);
    k_bsum<<<NBLK, SCAN_B, 0, stream>>>(deg, bsum);
    k_bscan<<<1, 128, 0, stream>>>(bsum, row_off);
    k_cscan<<<NBLK, SCAN_B, 0, stream>>>(deg, bsum, row_off, invd);
    k_fill<<<(EE + 255) / 256, 256, 0, stream>>>(src, dst, row_off, cursor, csr);
    k_x2bf<<<(NN * DD / 4 + 255) / 256, 256, 0, stream>>>(x, xb);

    const float* hin = x;
    const u16* hbin = xb;
    float* houts[3] = {h0, h1, h0};
    u16* hbouts[3] = {hb0, hb1, (u16*)nullptr};
    for (int l = 0; l < 3; ++l) {
        k_agg<<<(NN + 3) / 4, 256, 0, stream>>>(hbin, row_off, csr, invd, ag);
        k_gemm<<<(NN + 63) / 64, 256, 0, stream>>>(
            hin, ag, Ws + l * DD * DD, Wn + l * DD * DD, bc + l * DD,
            (l < 2) ? gm + l * DD : (const float*)nullptr,
            (l < 2) ? bt + l * DD : (const float*)nullptr,
            houts[l], hbouts[l],
            (l == 2) ? out + (size_t)NN * CC : (float*)nullptr,
            (l < 2) ? 1 : 0);
        hin = houts[l];
        hbin = hbouts[l];
    }
    k_logits<<<(NN + 63) / 64, 256, 0, stream>>>(h0, Wo, bo, out);
}

// Round 6
// 383.334 us; speedup vs baseline: 1.8708x; 1.3394x over previous
//
#include <hip/hip_runtime.h>

#define NN 50000
#define EE 800000
#define DD 128
#define CC 64
#define SCAN_B 512
#define NBLK ((NN + SCAN_B - 1) / SCAN_B)   // 98
#define LDA 264    // LDS A row stride in u16: 256 data + 8 pad (2-way bank alias = free)

typedef unsigned short u16;
typedef unsigned int u32;
typedef __attribute__((ext_vector_type(8))) short short8;   // 8 bf16
typedef __attribute__((ext_vector_type(4))) float f32x4;

__device__ __forceinline__ float bf2f(u16 u) {
    union { u32 i; float f; } v; v.i = ((u32)u) << 16; return v.f;
}
__device__ __forceinline__ u16 f2bf(float f) {
    union { float f; u32 i; } v; v.f = f;
    u32 x = v.i;
    u32 r = x + 0x7fffu + ((x >> 16) & 1u);   // round-to-nearest-even
    return (u16)(r >> 16);
}

// ---------------- degree ----------------

__global__ __launch_bounds__(256) void k_degree(const int* __restrict__ dst,
                                                int* __restrict__ deg) {
    int e = blockIdx.x * 256 + threadIdx.x;
    if (e < EE) atomicAdd(&deg[dst[e]], 1);
}

// ---------------- 3-phase exclusive scan over deg -> row_off, inv_deg ----------------

__global__ __launch_bounds__(512) void k_bsum(const int* __restrict__ deg,
                                              int* __restrict__ bsum) {
    __shared__ int ws[8];
    int b = blockIdx.x, t = threadIdx.x;
    int i = b * SCAN_B + t;
    int x = (i < NN) ? deg[i] : 0;
#pragma unroll
    for (int o = 1; o < 64; o <<= 1) x += __shfl_xor(x, o);
    if ((t & 63) == 0) ws[t >> 6] = x;
    __syncthreads();
    if (t == 0) {
        int s = 0;
#pragma unroll
        for (int w = 0; w < 8; ++w) s += ws[w];
        bsum[b] = s;
    }
}

__global__ __launch_bounds__(128) void k_bscan(int* __restrict__ bsum,
                                               int* __restrict__ row_off) {
    __shared__ int w0sum;
    int t = threadIdx.x;
    int v = (t < NBLK) ? bsum[t] : 0;
    int x = v;
#pragma unroll
    for (int o = 1; o < 64; o <<= 1) {
        int y = __shfl_up(x, o, 64);
        if ((t & 63) >= o) x += y;
    }
    if (t == 63) w0sum = x;
    __syncthreads();
    if (t >= 64) x += w0sum;
    if (t < NBLK) bsum[t] = x - v;       // exclusive
    if (t == NBLK - 1) row_off[NN] = x;  // total == EE
}

__global__ __launch_bounds__(512) void k_cscan(const int* __restrict__ deg,
                                               const int* __restrict__ bsum,
                                               int* __restrict__ row_off,
                                               float* __restrict__ inv_deg) {
    __shared__ int ws[8];
    int b = blockIdx.x, t = threadIdx.x;
    int i = b * SCAN_B + t;
    int v = (i < NN) ? deg[i] : 0;
    int lane = t & 63, wid = t >> 6;
    int x = v;
#pragma unroll
    for (int o = 1; o < 64; o <<= 1) {
        int y = __shfl_up(x, o, 64);
        if (lane >= o) x += y;
    }
    if (lane == 63) ws[wid] = x;
    __syncthreads();
    int woff = 0;
    for (int w = 0; w < wid; ++w) woff += ws[w];
    if (i < NN) {
        row_off[i] = bsum[b] + woff + x - v;
        inv_deg[i] = 1.0f / fmaxf((float)v, 1.0f);
    }
}

__global__ __launch_bounds__(256) void k_fill(const int* __restrict__ src,
                                              const int* __restrict__ dst,
                                              const int* __restrict__ row_off,
                                              int* __restrict__ cursor,
                                              int* __restrict__ csr) {
    int e = blockIdx.x * 256 + threadIdx.x;
    if (e < EE) {
        int d = dst[e];
        int pos = atomicAdd(&cursor[d], 1);
        csr[row_off[d] + pos] = src[e];
    }
}

// ---------------- x -> bf16 shadow ----------------

__global__ __launch_bounds__(256) void k_x2bf(const float* __restrict__ x,
                                              u16* __restrict__ xb) {
    int i = (blockIdx.x * 256 + threadIdx.x) * 4;
    if (i < NN * DD) {
        float4 v = *(const float4*)(x + i);
        uint2 p;
        p.x = (u32)f2bf(v.x) | ((u32)f2bf(v.y) << 16);
        p.y = (u32)f2bf(v.z) | ((u32)f2bf(v.w) << 16);
        *(uint2*)(xb + i) = p;
    }
}

// ---------------- weight pack: [Ws;Wn] (256x128) -> MFMA B-fragment order, bf16 ----------------
// frag (ks,nt,lane) holds B[ks*32 + (lane>>4)*8 + j][nt*16 + (lane&15)], j=0..7 contiguous.

__global__ __launch_bounds__(256) void k_wpack(const float* __restrict__ Ws,
                                               const float* __restrict__ Wn,
                                               u16* __restrict__ wpk) {
    int tid = blockIdx.x * 256 + threadIdx.x;   // 3 layers * 4096 frags
    if (tid >= 3 * 4096) return;
    int layer = tid >> 12;
    int rem = tid & 4095;
    int ks = rem >> 9;
    int nt = (rem >> 6) & 7;
    int lane = rem & 63;
    int n = nt * 16 + (lane & 15);
    int kb = ks * 32 + (lane >> 4) * 8;
    u16 o[8];
#pragma unroll
    for (int j = 0; j < 8; ++j) {
        int k = kb + j;
        float w = (k < DD) ? Ws[layer * DD * DD + k * DD + n]
                           : Wn[layer * DD * DD + (k - DD) * DD + n];
        o[j] = f2bf(w);
    }
    uint4 pk;
    pk.x = (u32)o[0] | ((u32)o[1] << 16);
    pk.y = (u32)o[2] | ((u32)o[3] << 16);
    pk.z = (u32)o[4] | ((u32)o[5] << 16);
    pk.w = (u32)o[6] | ((u32)o[7] << 16);
    *(uint4*)(wpk + (size_t)tid * 8) = pk;
}

// ---------------- mean aggregation: one wave per node, bf16 in / bf16 out ----------------

__global__ __launch_bounds__(256) void k_agg(const u16* __restrict__ hb,
                                             const int* __restrict__ row_off,
                                             const int* __restrict__ csr,
                                             const float* __restrict__ inv_deg,
                                             u16* __restrict__ agb) {
    int wave = blockIdx.x * 4 + (threadIdx.x >> 6);
    int lane = threadIdx.x & 63;
    if (wave >= NN) return;
    int half = lane >> 5;
    int l32 = lane & 31;
    int beg = row_off[wave], end = row_off[wave + 1];
    float a0 = 0.f, a1 = 0.f, a2 = 0.f, a3 = 0.f;
#pragma unroll 4
    for (int e = beg + half; e < end; e += 2) {
        int s = csr[e];
        uint2 u = *(const uint2*)(hb + (size_t)s * DD + l32 * 4);
        a0 += bf2f((u16)(u.x & 0xffffu));
        a1 += bf2f((u16)(u.x >> 16));
        a2 += bf2f((u16)(u.y & 0xffffu));
        a3 += bf2f((u16)(u.y >> 16));
    }
    a0 += __shfl_xor(a0, 32);
    a1 += __shfl_xor(a1, 32);
    a2 += __shfl_xor(a2, 32);
    a3 += __shfl_xor(a3, 32);
    if (half == 0) {
        float sc = inv_deg[wave];
        uint2 p;
        p.x = (u32)f2bf(a0 * sc) | ((u32)f2bf(a1 * sc) << 16);
        p.y = (u32)f2bf(a2 * sc) | ((u32)f2bf(a3 * sc) << 16);
        *(uint2*)(agb + (size_t)wave * DD + l32 * 4) = p;
    }
}

// ---------------- MFMA fused SAGEConv layer ----------------
// block = 256 thr = 4 waves, 64 nodes; wave handles 16 rows x 128 cols.
// A = [h_bf16 | agg_bf16] (K=256) staged to LDS; B = packed fragments (k_wpack).
// Epilogue: +bias, +fp32 residual, [ReLU+LN] in C-layout, store fp32 + bf16 shadow.

__global__ __launch_bounds__(256) void k_gemm(const float* __restrict__ h_in,
                                              const u16* __restrict__ hb,
                                              const u16* __restrict__ agb,
                                              const u16* __restrict__ wpk,
                                              const float* __restrict__ bias,
                                              const float* __restrict__ gmm,
                                              const float* __restrict__ bet,
                                              float* __restrict__ h_out,
                                              u16* __restrict__ hb_out,
                                              float* __restrict__ emb_out,
                                              int do_ln) {
    __shared__ u16 A[64 * LDA];   // 33792 B
    int t = threadIdx.x;
    int b0 = blockIdx.x * 64;

    // stage A: h half (cols 0-127) and agg half (cols 128-255), 16B chunks
#pragma unroll
    for (int j = 0; j < 4; ++j) {
        int idx = t + 256 * j;       // 1024 chunks: 64 rows x 16
        int r = idx >> 4;
        int c = idx & 15;            // chunk of 8 u16
        int node = b0 + r;
        uint4 v = make_uint4(0, 0, 0, 0), w = make_uint4(0, 0, 0, 0);
        if (node < NN) {
            v = *(const uint4*)(hb + (size_t)node * DD + c * 8);
            w = *(const uint4*)(agb + (size_t)node * DD + c * 8);
        }
        *(uint4*)&A[r * LDA + c * 8] = v;
        *(uint4*)&A[r * LDA + 128 + c * 8] = w;
    }
    __syncthreads();

    int wv = t >> 6, lane = t & 63;
    int m = lane & 15, q = lane >> 4;

    f32x4 acc[8];
#pragma unroll
    for (int nt = 0; nt < 8; ++nt) acc[nt] = (f32x4)(0.f);

    const u16* Arow = &A[(wv * 16 + m) * LDA + q * 8];
    const short8* wp = (const short8*)wpk;
#pragma unroll
    for (int ks = 0; ks < 8; ++ks) {
        short8 af = *(const short8*)(Arow + ks * 32);
        const short8* bp = wp + (ks * 8) * 64 + lane;
#pragma unroll
        for (int nt = 0; nt < 8; ++nt) {
            short8 bf = bp[nt * 64];
            acc[nt] = __builtin_amdgcn_mfma_f32_16x16x32_bf16(af, bf, acc[nt], 0, 0, 0);
        }
    }

    // per-lane column constants
    float bcol[8], gcol[8], ecol[8];
#pragma unroll
    for (int nt = 0; nt < 8; ++nt) {
        bcol[nt] = bias[nt * 16 + m];
        if (do_ln) { gcol[nt] = gmm[nt * 16 + m]; ecol[nt] = bet[nt * 16 + m]; }
    }

    // epilogue per C-row j: row = q*4+j, node = b0 + wv*16 + q*4 + j
#pragma unroll
    for (int j = 0; j < 4; ++j) {
        int node = b0 + wv * 16 + q * 4 + j;
        bool ok = node < NN;
        const float* hr = h_in + (size_t)node * DD;
        float v[8];
        float s = 0.f, qq = 0.f;
#pragma unroll
        for (int nt = 0; nt < 8; ++nt) {
            float x = acc[nt][j] + bcol[nt];
            if (ok) x += hr[nt * 16 + m];        // fp32 residual
            if (do_ln) {
                x = fmaxf(x, 0.f);
                s += x; qq += x * x;
            }
            v[nt] = x;
        }
        if (do_ln) {
#pragma unroll
            for (int o = 1; o < 16; o <<= 1) {   // reduce across the quad's 16 lanes
                s += __shfl_xor(s, o);
                qq += __shfl_xor(qq, o);
            }
            float mu = s * (1.0f / 128.0f);
            float var = fmaxf(qq * (1.0f / 128.0f) - mu * mu, 0.f);
            float rs = rsqrtf(var + 1e-5f);
#pragma unroll
            for (int nt = 0; nt < 8; ++nt)
                v[nt] = gcol[nt] * (v[nt] - mu) * rs + ecol[nt];
        }
        if (ok) {
            float* orow = h_out + (size_t)node * DD;
#pragma unroll
            for (int nt = 0; nt < 8; ++nt) orow[nt * 16 + m] = v[nt];
            if (hb_out) {
                u16* brow = hb_out + (size_t)node * DD;
#pragma unroll
                for (int nt = 0; nt < 8; ++nt) brow[nt * 16 + m] = f2bf(v[nt]);
            }
            if (emb_out) {
                float* erow = emb_out + (size_t)node * DD;
#pragma unroll
                for (int nt = 0; nt < 8; ++nt) erow[nt * 16 + m] = v[nt];
            }
        }
    }
}

// ---------------- output head: logits = h @ Wout + bout (fp32 vector) ----------------

__device__ __forceinline__ void stage_tile(const float* __restrict__ g, int b0,
                                           float* __restrict__ tile, int t) {
#pragma unroll
    for (int j = 0; j < 8; ++j) {
        int idx = t + 256 * j;
        int r = idx >> 5;
        int c = idx & 31;
        int node = b0 + r;
        float4 f = make_float4(0.f, 0.f, 0.f, 0.f);
        if (node < NN) f = *(const float4*)(g + (size_t)node * DD + c * 4);
        *(float4*)&tile[r * DD + c * 4] = f;
    }
}

__global__ __launch_bounds__(256) void k_logits(const float* __restrict__ h,
                                                const float* __restrict__ Wo,
                                                const float* __restrict__ bo,
                                                float* __restrict__ out) {
    __shared__ float tile[64 * DD];
    int t = threadIdx.x;
    int b0 = blockIdx.x * 64;
    int cg = t & 15;
    int ng = t >> 4;
    stage_tile(h, b0, tile, t);
    __syncthreads();
    float acc[4][4];
#pragma unroll
    for (int i = 0; i < 4; ++i)
#pragma unroll
        for (int j = 0; j < 4; ++j) acc[i][j] = 0.f;
    for (int k = 0; k < DD; k += 4) {
        float4 w0 = *(const float4*)(Wo + (k + 0) * CC + cg * 4);
        float4 w1 = *(const float4*)(Wo + (k + 1) * CC + cg * 4);
        float4 w2 = *(const float4*)(Wo + (k + 2) * CC + cg * 4);
        float4 w3 = *(const float4*)(Wo + (k + 3) * CC + cg * 4);
#pragma unroll
        for (int i = 0; i < 4; ++i) {
            float4 hv = *(const float4*)&tile[(ng * 4 + i) * DD + k];
            acc[i][0] = fmaf(hv.x, w0.x, fmaf(hv.y, w1.x, fmaf(hv.z, w2.x, fmaf(hv.w, w3.x, acc[i][0]))));
            acc[i][1] = fmaf(hv.x, w0.y, fmaf(hv.y, w1.y, fmaf(hv.z, w2.y, fmaf(hv.w, w3.y, acc[i][1]))));
            acc[i][2] = fmaf(hv.x, w0.z, fmaf(hv.y, w1.z, fmaf(hv.z, w2.z, fmaf(hv.w, w3.z, acc[i][2]))));
            acc[i][3] = fmaf(hv.x, w0.w, fmaf(hv.y, w1.w, fmaf(hv.z, w2.w, fmaf(hv.w, w3.w, acc[i][3]))));
        }
    }
    float4 b4 = *(const float4*)(bo + cg * 4);
#pragma unroll
    for (int i = 0; i < 4; ++i) {
        int node = b0 + ng * 4 + i;
        if (node < NN) {
            *(float4*)(out + (size_t)node * CC + cg * 4) =
                make_float4(acc[i][0] + b4.x, acc[i][1] + b4.y,
                            acc[i][2] + b4.z, acc[i][3] + b4.w);
        }
    }
}

// ---------------- launch ----------------

extern "C" void kernel_launch(void* const* d_in, const int* in_sizes, int n_in,
                              void* d_out, int out_size, void* d_ws, size_t ws_size,
                              hipStream_t stream) {
    const float* x  = (const float*)d_in[0];
    const int* src  = (const int*)d_in[1];
    const int* dst  = (const int*)d_in[2];
    const float* Ws = (const float*)d_in[3];
    const float* Wn = (const float*)d_in[4];
    const float* bc = (const float*)d_in[5];
    const float* gm = (const float*)d_in[6];
    const float* bt = (const float*)d_in[7];
    const float* Wo = (const float*)d_in[8];
    const float* bo = (const float*)d_in[9];
    float* out = (float*)d_out;   // fp32: logits [NN*CC] then embedding [NN*DD]

    char* p = (char*)d_ws;
    auto alloc = [&](size_t bytes) { void* r = (void*)p; p += (bytes + 255) & ~(size_t)255; return r; };
    float* h0    = (float*)alloc((size_t)NN * DD * 4);
    float* h1    = (float*)alloc((size_t)NN * DD * 4);
    u16* xb      = (u16*)alloc((size_t)NN * DD * 2);
    u16* hb0     = (u16*)alloc((size_t)NN * DD * 2);
    u16* hb1     = (u16*)alloc((size_t)NN * DD * 2);
    u16* agb     = (u16*)alloc((size_t)NN * DD * 2);
    u16* wpk     = (u16*)alloc((size_t)3 * 4096 * 8 * 2);
    float* invd  = (float*)alloc(NN * 4);
    int* deg     = (int*)alloc(NN * 4);
    int* row_off = (int*)alloc((NN + 1) * 4);
    int* cursor  = (int*)alloc(NN * 4);
    int* bsum    = (int*)alloc(NBLK * 4);
    int* csr     = (int*)alloc(EE * 4);

    hipMemsetAsync(deg, 0, NN * 4, stream);
    hipMemsetAsync(cursor, 0, NN * 4, stream);

    k_degree<<<(EE + 255) / 256, 256, 0, stream>>>(dst, deg);
    k_bsum<<<NBLK, SCAN_B, 0, stream>>>(deg, bsum);
    k_bscan<<<1, 128, 0, stream>>>(bsum, row_off);
    k_cscan<<<NBLK, SCAN_B, 0, stream>>>(deg, bsum, row_off, invd);
    k_fill<<<(EE + 255) / 256, 256, 0, stream>>>(src, dst, row_off, cursor, csr);
    k_x2bf<<<(NN * DD / 4 + 255) / 256, 256, 0, stream>>>(x, xb);
    k_wpack<<<(3 * 4096 + 255) / 256, 256, 0, stream>>>(Ws, Wn, wpk);

    const float* hin = x;
    const u16* hbin = xb;
    float* houts[3] = {h0, h1, h0};
    u16* hbouts[3] = {hb0, hb1, (u16*)nullptr};
    for (int l = 0; l < 3; ++l) {
        k_agg<<<(NN + 3) / 4, 256, 0, stream>>>(hbin, row_off, csr, invd, agb);
        k_gemm<<<(NN + 63) / 64, 256, 0, stream>>>(
            hin, hbin, agb, wpk + (size_t)l * 4096 * 8,
            bc + l * DD,
            (l < 2) ? gm + l * DD : (const float*)nullptr,
            (l < 2) ? bt + l * DD : (const float*)nullptr,
            houts[l], hbouts[l],
            (l == 2) ? out + (size_t)NN * CC : (float*)nullptr,
            (l < 2) ? 1 : 0);
        hin = houts[l];
        hbin = hbouts[l];
    }
    k_logits<<<(NN + 63) / 64, 256, 0, stream>>>(h0, Wo, bo, out);
}